// Round 5
// baseline (447.364 us; speedup 1.0000x reference)
//
#include <hip/hip_runtime.h>
#include <hip/hip_bf16.h>
#include <math.h>

// Problem constants
#define S_LEN   2048
#define BATCH   4
#define DMODEL  1024
#define NHEAD   16
#define DHEAD   64
#define MROWS   (S_LEN * BATCH)   // 8192 rows in flattened (s,b) order

typedef __bf16 bf16;
typedef __bf16 bf16x8 __attribute__((ext_vector_type(8)));
typedef __bf16 bf16x4 __attribute__((ext_vector_type(4)));
typedef short  short4_t __attribute__((ext_vector_type(4)));
typedef float  f32x4  __attribute__((ext_vector_type(4)));

#define LOG2E 1.4426950408889634f

// address-space casts for global_load_lds (direct global->LDS DMA)
#define AS1C(p) (const __attribute__((address_space(1))) void*)(p)
#define AS3(p)  (__attribute__((address_space(3))) void*)(p)

// ---------------------------------------------------------------------------
// fp32 -> bf16 cast, 8 elems/thread
// ---------------------------------------------------------------------------
__global__ __launch_bounds__(256) void cast_bf16(const float* __restrict__ in,
                                                 bf16* __restrict__ out, int n8) {
    int i = blockIdx.x * 256 + threadIdx.x;
    if (i >= n8) return;
    const float4* p = (const float4*)in;
    float4 a = p[i * 2], b = p[i * 2 + 1];
    bf16x8 o;
    o[0] = (bf16)a.x; o[1] = (bf16)a.y; o[2] = (bf16)a.z; o[3] = (bf16)a.w;
    o[4] = (bf16)b.x; o[5] = (bf16)b.y; o[6] = (bf16)b.z; o[7] = (bf16)b.w;
    *(bf16x8*)(out + (size_t)i * 8) = o;
}

// ---------------------------------------------------------------------------
// C[M,N] = A[M,K] * W[N,K]^T + bias[N]   (optionally * per-head Q-scale)
// m97 pattern: unpadded BK=32 LDS tiles staged via global_load_lds width=16.
// LDS dest is wave-uniform base + lane*16 (contiguous in lane order) — the
// global address permutation supplies row-major placement.
// ---------------------------------------------------------------------------
template <typename OUT_T, bool QS>
__global__ __launch_bounds__(256) void gemm_bt(const bf16* __restrict__ A,
                                               const bf16* __restrict__ W,
                                               const float* __restrict__ bias,
                                               const float* __restrict__ beta,
                                               OUT_T* __restrict__ C) {
    constexpr int N = DMODEL, K = DMODEL;
    constexpr int BM = 128, BN = 128, BK = 32;
    __shared__ __align__(16) bf16 sA[BM * BK];   // 8 KB, unpadded
    __shared__ __align__(16) bf16 sB[BN * BK];   // 8 KB

    const int t    = threadIdx.x;
    const int lane = t & 63;
    const int wave = t >> 6;
    const int bm = blockIdx.y * BM;
    const int bn = blockIdx.x * BN;
    const int wm = (wave & 1) * 64;
    const int wn = (wave >> 1) * 64;
    const int lq = lane & 15;
    const int lg = lane >> 4;

    // staging: wave w, issue j in {0,1}: rows w*32 + j*16 + lane/4, col (lane&3)*8
    const int grow = wave * 32 + (lane >> 2);
    const int gcol = (lane & 3) * 8;
    const bf16* Ap = A + (size_t)(bm + grow) * K + gcol;
    const bf16* Wp = W + (size_t)(bn + grow) * K + gcol;
    bf16* la0 = &sA[(wave * 32) * BK];   // wave-uniform LDS bases
    bf16* lb0 = &sB[(wave * 32) * BK];

    f32x4 acc[4][4] = {};

    for (int k0 = 0; k0 < K; k0 += BK) {
        __syncthreads();   // previous iteration's LDS reads complete
        __builtin_amdgcn_global_load_lds(AS1C(Ap + k0),                   AS3(la0),           16, 0, 0);
        __builtin_amdgcn_global_load_lds(AS1C(Ap + (size_t)16 * K + k0),  AS3(la0 + 16 * BK), 16, 0, 0);
        __builtin_amdgcn_global_load_lds(AS1C(Wp + k0),                   AS3(lb0),           16, 0, 0);
        __builtin_amdgcn_global_load_lds(AS1C(Wp + (size_t)16 * K + k0),  AS3(lb0 + 16 * BK), 16, 0, 0);
        __syncthreads();   // DMA complete + visible

        const int koff = lg * 8;
        bf16x8 af[4], bfr[4];
#pragma unroll
        for (int mt = 0; mt < 4; mt++)
            af[mt] = *(const bf16x8*)&sA[(wm + mt * 16 + lq) * BK + koff];
#pragma unroll
        for (int nt = 0; nt < 4; nt++)
            bfr[nt] = *(const bf16x8*)&sB[(wn + nt * 16 + lq) * BK + koff];
#pragma unroll
        for (int mt = 0; mt < 4; mt++)
#pragma unroll
            for (int nt = 0; nt < 4; nt++)
                acc[mt][nt] = __builtin_amdgcn_mfma_f32_16x16x32_bf16(
                    af[mt], bfr[nt], acc[mt][nt], 0, 0, 0);
    }

    const int cr = lg * 4;
    const int cc = lq;
#pragma unroll
    for (int nt = 0; nt < 4; nt++) {
        const int col = bn + wn + nt * 16 + cc;
        const float bv = bias[col];
        float sc = 1.0f;
        if (QS) sc = LOG2E / (__expf(beta[col >> 6]) * 8.0f);
#pragma unroll
        for (int mt = 0; mt < 4; mt++) {
            const int row = bm + wm + mt * 16 + cr;
#pragma unroll
            for (int r = 0; r < 4; r++) {
                float v = (acc[mt][nt][r] + bv) * sc;
                C[(size_t)(row + r) * N + col] = (OUT_T)v;
            }
        }
    }
}

// ---------------------------------------------------------------------------
// V[s][b][h*64+d] -> Vt[b][h][d][s]  via per-thread 8x8 bf16 register
// transpose (3-stage butterfly). Coalesced 16B reads and writes; no LDS.
// ---------------------------------------------------------------------------
__global__ __launch_bounds__(256) void transpose_v(const bf16* __restrict__ V,
                                                   bf16* __restrict__ Vt) {
    const int t = threadIdx.x;
    const int h = blockIdx.y, b = blockIdx.z;
    const int s0 = blockIdx.x * 256 + (t >> 3) * 8;
    const int d0 = (t & 7) * 8;

    bf16x8 r[8], u[8], v2[8], w[8];
#pragma unroll
    for (int i = 0; i < 8; i++)
        r[i] = *(const bf16x8*)&V[((size_t)(s0 + i) * BATCH + b) * DMODEL + h * DHEAD + d0];
#pragma unroll
    for (int i = 0; i < 4; i++) {
        u[i]     = __builtin_shufflevector(r[i], r[i + 4], 0, 1, 2, 3, 8, 9, 10, 11);
        u[i + 4] = __builtin_shufflevector(r[i], r[i + 4], 4, 5, 6, 7, 12, 13, 14, 15);
    }
#pragma unroll
    for (int g = 0; g < 2; g++)
#pragma unroll
        for (int i = 0; i < 2; i++) {
            int a = g * 4 + i;
            v2[a]     = __builtin_shufflevector(u[a], u[a + 2], 0, 1, 8, 9, 4, 5, 12, 13);
            v2[a + 2] = __builtin_shufflevector(u[a], u[a + 2], 2, 3, 10, 11, 6, 7, 14, 15);
        }
#pragma unroll
    for (int i = 0; i < 8; i += 2) {
        w[i]     = __builtin_shufflevector(v2[i], v2[i + 1], 0, 8, 2, 10, 4, 12, 6, 14);
        w[i + 1] = __builtin_shufflevector(v2[i], v2[i + 1], 1, 9, 3, 11, 5, 13, 7, 15);
    }
#pragma unroll
    for (int j = 0; j < 8; j++)
        *(bf16x8*)&Vt[((size_t)((b * NHEAD + h) * DHEAD + d0 + j)) * S_LEN + s0] = w[j];
}

// ---------------------------------------------------------------------------
// Flash attention, causal + zero-sink, keys-split waves — BARRIER-FREE K-loop.
// Each wave owns keys [wave*16, wave*16+16) of every tile, and those are the
// ONLY K rows / Vt columns it touches — so K and Vt fragments are loaded
// directly global->registers (L2/L3-resident slabs). No LDS, no __syncthreads
// until the epilogue cross-wave O^T reduction.
// Register-array indices all compile-time constant (round-3 lesson).
// ---------------------------------------------------------------------------
__global__ __launch_bounds__(256, 3) void attn_kernel(const bf16* __restrict__ Q,
                                                      const bf16* __restrict__ K,
                                                      const bf16* __restrict__ Vt,
                                                      bf16* __restrict__ O) {
    __shared__ __align__(16) float sO[64 * 65];   // 16640 B (epilogue only)
    __shared__ __align__(16) float sL[256];       // 1024 B

    const int t    = threadIdx.x;
    const int lane = t & 63;
    const int wave = t >> 6;
    const int lq = lane & 15;
    const int lg = lane >> 4;
    const int qi = (int)gridDim.x - 1 - (int)blockIdx.x;  // heavy tiles first
    const int h = blockIdx.y;
    const int b = blockIdx.z;
    const int qb = qi * 64;

    // Loop-invariant Q fragments (B-operand of the St MFMA): [n=q][k=dh]
    bf16x8 qf[4][2];
#pragma unroll
    for (int nt = 0; nt < 4; nt++)
#pragma unroll
        for (int kc = 0; kc < 2; kc++)
            qf[nt][kc] = *(const bf16x8*)
                &Q[((size_t)(qb + nt * 16 + lq) * BATCH + b) * DMODEL + h * DHEAD + kc * 32 + lg * 8];

    f32x4 o_acc[4][4] = {};      // o_acc[dt][nt][r]: O^T row d=dt*16+lg*4+r, col q=nt*16+lq
    float l_lane[4] = {0.f, 0.f, 0.f, 0.f};

    // per-lane global bases for this wave's private key slice
    const size_t krow = (size_t)BATCH * DMODEL;   // K row stride (s-dim)
    const bf16* Kp = K + ((size_t)(wave * 16 + lq) * BATCH + b) * DMODEL + h * DHEAD + lg * 8;
    const bf16* Vp = Vt + ((size_t)(b * NHEAD + h) * DHEAD + lq) * S_LEN + wave * 16 + lg * 4;

    for (int kt = 0; kt <= qi; kt++) {
        const int kb = kt * 64;

        // direct global->register fragment loads (no LDS, no barrier)
        const bf16* Kq = Kp + (size_t)kb * krow;
        bf16x8 kf0 = *(const bf16x8*)Kq;
        bf16x8 kf1 = *(const bf16x8*)(Kq + 32);
        bf16x4 va[4];
#pragma unroll
        for (int dt = 0; dt < 4; dt++)
            va[dt] = *(const bf16x4*)(Vp + (size_t)dt * 16 * S_LEN + kb);

        // St[key][q]: this wave's 16 keys x 64 q  (A = K rows, B = Q rows)
        f32x4 st[4];
#pragma unroll
        for (int nt = 0; nt < 4; nt++) {
            f32x4 a = {};
            a = __builtin_amdgcn_mfma_f32_16x16x32_bf16(kf0, qf[nt][0], a, 0, 0, 0);
            a = __builtin_amdgcn_mfma_f32_16x16x32_bf16(kf1, qf[nt][1], a, 0, 0, 0);
            st[nt] = a;
        }

        // causal mask on the diagonal tile: key_local > q_local -> -inf
        if (kt == qi) {
#pragma unroll
            for (int nt = 0; nt < 4; nt++)
#pragma unroll
                for (int r = 0; r < 4; r++)
                    if (wave * 16 + lg * 4 + r > nt * 16 + lq) st[nt][r] = -1e30f;
        }

        // P^T = exp2(St) (scores pre-scaled by log2e), pack to bf16, track l
        short4_t pf[4];
#pragma unroll
        for (int nt = 0; nt < 4; nt++) {
            float p0 = __builtin_amdgcn_exp2f(st[nt][0]);
            float p1 = __builtin_amdgcn_exp2f(st[nt][1]);
            float p2 = __builtin_amdgcn_exp2f(st[nt][2]);
            float p3 = __builtin_amdgcn_exp2f(st[nt][3]);
            l_lane[nt] += (p0 + p1) + (p2 + p3);
            bf16x4 pv;
            pv[0] = (bf16)p0; pv[1] = (bf16)p1; pv[2] = (bf16)p2; pv[3] = (bf16)p3;
            pf[nt] = __builtin_bit_cast(short4_t, pv);
        }

        // O^T += Vt(d x key16) * P^T   via mfma_f32_16x16x16_bf16
#pragma unroll
        for (int dt = 0; dt < 4; dt++) {
            short4_t vva = __builtin_bit_cast(short4_t, va[dt]);
#pragma unroll
            for (int nt = 0; nt < 4; nt++)
                o_acc[dt][nt] = __builtin_amdgcn_mfma_f32_16x16x16bf16_1k(
                    vva, pf[nt], o_acc[dt][nt], 0, 0, 0);
        }
    }

    // ---------------- epilogue: cross-wave reduction ----------------
    // per-wave l: sum over lg groups (lanes with equal lq), then stash
#pragma unroll
    for (int nt = 0; nt < 4; nt++) {
        float v = l_lane[nt];
        v += __shfl_xor(v, 16);
        v += __shfl_xor(v, 32);
        if (lg == 0) sL[wave * 64 + nt * 16 + lq] = v;
    }

    // O^T reduction rounds. Round rd: wave w handles slice dt=(w+rd)&3
    // (disjoint across waves); dtc compile-time constant via if-chain.
#pragma unroll
    for (int rd = 0; rd < 4; rd++) {
#pragma unroll
        for (int dtc = 0; dtc < 4; dtc++) {
            if (((wave + rd) & 3) == dtc) {
                if (rd == 0) {
#pragma unroll
                    for (int nt = 0; nt < 4; nt++)
#pragma unroll
                        for (int r = 0; r < 4; r++)
                            sO[(dtc * 16 + lg * 4 + r) * 65 + nt * 16 + lq] = o_acc[dtc][nt][r];
                } else {
#pragma unroll
                    for (int nt = 0; nt < 4; nt++)
#pragma unroll
                        for (int r = 0; r < 4; r++)
                            sO[(dtc * 16 + lg * 4 + r) * 65 + nt * 16 + lq] += o_acc[dtc][nt][r];
                }
            }
        }
        __syncthreads();
    }

    // final: wave stores dt=wave slice of O = O^T / l  (sink adds 1 to l)
    const int dt = wave;
    float rec[4];
#pragma unroll
    for (int nt = 0; nt < 4; nt++) {
        float lt = 1.0f + sL[nt * 16 + lq] + sL[64 + nt * 16 + lq]
                 + sL[128 + nt * 16 + lq] + sL[192 + nt * 16 + lq];
        rec[nt] = 1.0f / lt;
    }
#pragma unroll
    for (int nt = 0; nt < 4; nt++) {
        bf16x4 ov;
#pragma unroll
        for (int r = 0; r < 4; r++)
            ov[r] = (bf16)(sO[(dt * 16 + lg * 4 + r) * 65 + nt * 16 + lq] * rec[nt]);
        *(bf16x4*)&O[((size_t)(qb + nt * 16 + lq) * BATCH + b) * DMODEL + h * DHEAD + dt * 16 + lg * 4] = ov;
    }
}

// ---------------------------------------------------------------------------
extern "C" void kernel_launch(void* const* d_in, const int* in_sizes, int n_in,
                              void* d_out, int out_size, void* d_ws, size_t ws_size,
                              hipStream_t stream) {
    const float* x    = (const float*)d_in[0];
    // d_in[1] = attn_mask (pure causal -1e9; implemented structurally)
    const float* beta = (const float*)d_in[2];
    const float* Wq   = (const float*)d_in[3];
    const float* bq   = (const float*)d_in[4];
    const float* Wk   = (const float*)d_in[5];
    const float* bk   = (const float*)d_in[6];
    const float* Wv   = (const float*)d_in[7];
    const float* bv   = (const float*)d_in[8];
    const float* Wo   = (const float*)d_in[9];
    const float* bo   = (const float*)d_in[10];
    float* out = (float*)d_out;

    char* ws = (char*)d_ws;
    size_t off = 0;
    auto alloc = [&](size_t bytes) -> void* {
        void* p = ws + off;
        off += (bytes + 255) & ~(size_t)255;
        return p;
    };
    const size_t xbytes = (size_t)MROWS * DMODEL * sizeof(bf16);   // 16 MB
    const size_t wbytes = (size_t)DMODEL * DMODEL * sizeof(bf16);  // 2 MB
    bf16* xb  = (bf16*)alloc(xbytes);
    bf16* wqb = (bf16*)alloc(wbytes);
    bf16* wkb = (bf16*)alloc(wbytes);
    bf16* wvb = (bf16*)alloc(wbytes);
    bf16* wob = (bf16*)alloc(wbytes);
    bf16* qws = (bf16*)alloc(xbytes);
    bf16* kws = (bf16*)alloc(xbytes);
    bf16* vws = (bf16*)alloc(xbytes);
    bf16* vtb = (bf16*)alloc(xbytes);
    bf16* aob = (bf16*)alloc(xbytes);

    const int nx8 = MROWS * DMODEL / 8;
    const int nw8 = DMODEL * DMODEL / 8;
    cast_bf16<<<(nx8 + 255) / 256, 256, 0, stream>>>(x, xb, nx8);
    cast_bf16<<<(nw8 + 255) / 256, 256, 0, stream>>>(Wq, wqb, nw8);
    cast_bf16<<<(nw8 + 255) / 256, 256, 0, stream>>>(Wk, wkb, nw8);
    cast_bf16<<<(nw8 + 255) / 256, 256, 0, stream>>>(Wv, wvb, nw8);
    cast_bf16<<<(nw8 + 255) / 256, 256, 0, stream>>>(Wo, wob, nw8);

    dim3 ggrid(DMODEL / 128, MROWS / 128);   // (8, 64)
    gemm_bt<bf16, true ><<<ggrid, 256, 0, stream>>>(xb, wqb, bq, beta, qws);
    gemm_bt<bf16, false><<<ggrid, 256, 0, stream>>>(xb, wkb, bk, nullptr, kws);
    gemm_bt<bf16, false><<<ggrid, 256, 0, stream>>>(xb, wvb, bv, nullptr, vws);

    dim3 tgrid(S_LEN / 256, NHEAD, BATCH);   // (8, 16, 4)
    transpose_v<<<tgrid, 256, 0, stream>>>(vws, vtb);

    dim3 agrid(S_LEN / 64, NHEAD, BATCH);    // (32, 16, 4)
    attn_kernel<<<agrid, 256, 0, stream>>>(qws, kws, vtb, aob);

    gemm_bt<float, false><<<ggrid, 256, 0, stream>>>(aob, wob, bo, nullptr, out);
}

// Round 6
// 320.919 us; speedup vs baseline: 1.3940x; 1.3940x over previous
//
#include <hip/hip_runtime.h>
#include <hip/hip_bf16.h>
#include <math.h>

// Problem constants
#define S_LEN   2048
#define BATCH   4
#define DMODEL  1024
#define NHEAD   16
#define DHEAD   64
#define MROWS   (S_LEN * BATCH)   // 8192 rows in flattened (s,b) order

typedef __bf16 bf16;
typedef __bf16 bf16x8 __attribute__((ext_vector_type(8)));
typedef __bf16 bf16x4 __attribute__((ext_vector_type(4)));
typedef short  short4_t __attribute__((ext_vector_type(4)));
typedef float  f32x4  __attribute__((ext_vector_type(4)));

#define LOG2E 1.4426950408889634f

// address-space casts for global_load_lds (direct global->LDS DMA)
#define AS1C(p) (const __attribute__((address_space(1))) void*)(p)
#define AS3(p)  (__attribute__((address_space(3))) void*)(p)

// Packed-layout definitions (per (b,h) slab of 128 key-tiles x 1024 elems):
//  Kp: tile T (16 keys): elem[T*1024 + c*512 + (s%16 + 16*(u>>3))*8 + (u&7)]
//      = K[s][dh], c=dh>>5, u=dh&31.  Wave fragment kf_c = 16B at lane*16.
//  Vp: tile T, d-tile dt: elem[T*1024 + dt*256 + (dh%16 + 16*((s%16)>>2))*4
//      + (s%16)&3] = V[s][dh].  Wave fragment va[dt] = 8B at lane*8.

// ---------------------------------------------------------------------------
// fp32 -> bf16 cast, 8 elems/thread
// ---------------------------------------------------------------------------
__global__ __launch_bounds__(256) void cast_bf16(const float* __restrict__ in,
                                                 bf16* __restrict__ out, int n8) {
    int i = blockIdx.x * 256 + threadIdx.x;
    if (i >= n8) return;
    const float4* p = (const float4*)in;
    float4 a = p[i * 2], b = p[i * 2 + 1];
    bf16x8 o;
    o[0] = (bf16)a.x; o[1] = (bf16)a.y; o[2] = (bf16)a.z; o[3] = (bf16)a.w;
    o[4] = (bf16)b.x; o[5] = (bf16)b.y; o[6] = (bf16)b.z; o[7] = (bf16)b.w;
    *(bf16x8*)(out + (size_t)i * 8) = o;
}

// ---------------------------------------------------------------------------
// C[M,N] = A[M,K] * W[N,K]^T + bias[N], m97-style staging.
// EPI: 0 = plain bf16 with per-head Q-scale; 1 = KPACK; 2 = VPACK;
//      3 = plain f32.
// C-layout fact used by packing: row = s*BATCH+b with BATCH=4 means the 4
// r-values of an acc group are the 4 batches of one s (b=r, s=S0+lg).
// ---------------------------------------------------------------------------
template <int EPI>
__global__ __launch_bounds__(256) void gemm_bt(const bf16* __restrict__ A,
                                               const bf16* __restrict__ W,
                                               const float* __restrict__ bias,
                                               const float* __restrict__ beta,
                                               void* __restrict__ Cv) {
    constexpr int N = DMODEL, K = DMODEL;
    constexpr int BM = 128, BN = 128, BK = 32;
    __shared__ __align__(16) bf16 sA[BM * BK];   // 8 KB, unpadded
    __shared__ __align__(16) bf16 sB[BN * BK];   // 8 KB

    const int t    = threadIdx.x;
    const int lane = t & 63;
    const int wave = t >> 6;
    const int bm = blockIdx.y * BM;
    const int bn = blockIdx.x * BN;
    const int wm = (wave & 1) * 64;
    const int wn = (wave >> 1) * 64;
    const int lq = lane & 15;
    const int lg = lane >> 4;

    const int grow = wave * 32 + (lane >> 2);
    const int gcol = (lane & 3) * 8;
    const bf16* Ap = A + (size_t)(bm + grow) * K + gcol;
    const bf16* Wp = W + (size_t)(bn + grow) * K + gcol;
    bf16* la0 = &sA[(wave * 32) * BK];
    bf16* lb0 = &sB[(wave * 32) * BK];

    f32x4 acc[4][4] = {};

    for (int k0 = 0; k0 < K; k0 += BK) {
        __syncthreads();
        __builtin_amdgcn_global_load_lds(AS1C(Ap + k0),                  AS3(la0),           16, 0, 0);
        __builtin_amdgcn_global_load_lds(AS1C(Ap + (size_t)16 * K + k0), AS3(la0 + 16 * BK), 16, 0, 0);
        __builtin_amdgcn_global_load_lds(AS1C(Wp + k0),                  AS3(lb0),           16, 0, 0);
        __builtin_amdgcn_global_load_lds(AS1C(Wp + (size_t)16 * K + k0), AS3(lb0 + 16 * BK), 16, 0, 0);
        __syncthreads();

        const int koff = lg * 8;
        bf16x8 af[4], bfr[4];
#pragma unroll
        for (int mt = 0; mt < 4; mt++)
            af[mt] = *(const bf16x8*)&sA[(wm + mt * 16 + lq) * BK + koff];
#pragma unroll
        for (int nt = 0; nt < 4; nt++)
            bfr[nt] = *(const bf16x8*)&sB[(wn + nt * 16 + lq) * BK + koff];
#pragma unroll
        for (int mt = 0; mt < 4; mt++)
#pragma unroll
            for (int nt = 0; nt < 4; nt++)
                acc[mt][nt] = __builtin_amdgcn_mfma_f32_16x16x32_bf16(
                    af[mt], bfr[nt], acc[mt][nt], 0, 0, 0);
    }

    const int cr = lg * 4;   // C row offset within 16 = lg*4 + r
    const int cc = lq;       // C col offset within 16
    if (EPI == 0 || EPI == 3) {
#pragma unroll
        for (int nt = 0; nt < 4; nt++) {
            const int col = bn + wn + nt * 16 + cc;
            const float bv = bias[col];
            float sc = 1.0f;
            if (EPI == 0) sc = LOG2E / (__expf(beta[col >> 6]) * 8.0f);
#pragma unroll
            for (int mt = 0; mt < 4; mt++) {
                const int row = bm + wm + mt * 16 + cr;
#pragma unroll
                for (int r = 0; r < 4; r++) {
                    float v = (acc[mt][nt][r] + bv) * sc;
                    if (EPI == 0) ((bf16*)Cv)[(size_t)(row + r) * N + col] = (bf16)v;
                    else          ((float*)Cv)[(size_t)(row + r) * N + col] = v;
                }
            }
        }
    } else {
        // packed K / V epilogue
        bf16* out = (bf16*)Cv;
        const int h = (bn + wn) >> 6;   // wave-uniform head
#pragma unroll
        for (int mt = 0; mt < 4; mt++) {
            const int S0  = (bm + wm + mt * 16) >> 2;  // s of (lg=0,r=*)
            const int t16 = S0 >> 4;                   // key-tile index s/16
            const int m4  = (S0 >> 2) & 3;             // (S0&15)>>2
#pragma unroll
            for (int nt = 0; nt < 4; nt++) {
                const int col = bn + wn + nt * 16 + cc;
                const float bv = bias[col];
#pragma unroll
                for (int r = 0; r < 4; r++) {   // r = batch b
                    float v = acc[mt][nt][r] + bv;
                    size_t addr;
                    if (EPI == 1) {   // Kp
                        addr = ((size_t)((r * 16 + h) * 128 + t16)) * 1024
                             + (nt >> 1) * 512
                             + ((S0 & 15) + lg + 16 * ((nt & 1) * 2 + (lq >> 3))) * 8
                             + (lq & 7);
                    } else {          // Vp
                        addr = ((size_t)((r * 16 + h) * 128 + t16)) * 1024
                             + nt * 256 + (lq + 16 * m4) * 4 + lg;
                    }
                    out[addr] = (bf16)v;
                }
            }
        }
    }
}

// ---------------------------------------------------------------------------
// Flash attention, causal + zero-sink, keys-split waves — barrier-free K-loop
// with COALESCED packed-fragment loads (round-5 lesson: barrier-free alone is
// a loss if the loads are scattered; packed layouts give contiguous 0.5-1 KB
// wave loads). 1-deep register prefetch of tile kt+1. LDS only in epilogue.
// Register-array indices all compile-time constant (round-3 lesson).
// ---------------------------------------------------------------------------
__global__ __launch_bounds__(256, 3) void attn_kernel(const bf16* __restrict__ Q,
                                                      const bf16* __restrict__ Kp,
                                                      const bf16* __restrict__ Vp,
                                                      bf16* __restrict__ O) {
    __shared__ __align__(16) float sO[64 * 65];   // 16640 B (epilogue only)
    __shared__ __align__(16) float sL[256];       // 1024 B

    const int t    = threadIdx.x;
    const int lane = t & 63;
    const int wave = t >> 6;
    const int lq = lane & 15;
    const int lg = lane >> 4;
    const int qi = (int)gridDim.x - 1 - (int)blockIdx.x;  // heavy tiles first
    const int h = blockIdx.y;
    const int b = blockIdx.z;
    const int qb = qi * 64;

    // Loop-invariant Q fragments (B-operand of the St MFMA): [n=q][k=dh]
    bf16x8 qf[4][2];
#pragma unroll
    for (int nt = 0; nt < 4; nt++)
#pragma unroll
        for (int kc = 0; kc < 2; kc++)
            qf[nt][kc] = *(const bf16x8*)
                &Q[((size_t)(qb + nt * 16 + lq) * BATCH + b) * DMODEL + h * DHEAD + kc * 32 + lg * 8];

    f32x4 o_acc[4][4] = {};      // o_acc[dt][nt][r]: O^T row d=dt*16+lg*4+r, col q=nt*16+lq
    float l_lane[4] = {0.f, 0.f, 0.f, 0.f};

    const bf16* Kb = Kp + (size_t)(b * NHEAD + h) * 131072;   // 128 tiles * 1024
    const bf16* Vb = Vp + (size_t)(b * NHEAD + h) * 131072;

    // prefetch tile kt=0 (wave's private 16-key tile index = kt*4 + wave)
    {
        const bf16* K0 = Kb + (size_t)wave * 1024;
        const bf16* V0 = Vb + (size_t)wave * 1024;
        // loads issued below into cur regs
    }
    bf16x8 kc0 = *(const bf16x8*)(Kb + (size_t)wave * 1024 + lane * 8);
    bf16x8 kc1 = *(const bf16x8*)(Kb + (size_t)wave * 1024 + 512 + lane * 8);
    bf16x4 vc0 = *(const bf16x4*)(Vb + (size_t)wave * 1024 +   0 + lane * 4);
    bf16x4 vc1 = *(const bf16x4*)(Vb + (size_t)wave * 1024 + 256 + lane * 4);
    bf16x4 vc2 = *(const bf16x4*)(Vb + (size_t)wave * 1024 + 512 + lane * 4);
    bf16x4 vc3 = *(const bf16x4*)(Vb + (size_t)wave * 1024 + 768 + lane * 4);

    for (int kt = 0; kt <= qi; kt++) {
        // prefetch next tile (branchless: wraps to tile 0 on last iter, unused)
        const int tn = ((kt < qi) ? (kt + 1) : 0) * 4 + wave;
        const bf16* Kn = Kb + (size_t)tn * 1024;
        const bf16* Vn = Vb + (size_t)tn * 1024;
        bf16x8 kn0 = *(const bf16x8*)(Kn + lane * 8);
        bf16x8 kn1 = *(const bf16x8*)(Kn + 512 + lane * 8);
        bf16x4 vn0 = *(const bf16x4*)(Vn +   0 + lane * 4);
        bf16x4 vn1 = *(const bf16x4*)(Vn + 256 + lane * 4);
        bf16x4 vn2 = *(const bf16x4*)(Vn + 512 + lane * 4);
        bf16x4 vn3 = *(const bf16x4*)(Vn + 768 + lane * 4);

        // St[key][q]: this wave's 16 keys x 64 q  (A = K rows, B = Q rows)
        f32x4 st[4];
#pragma unroll
        for (int nt = 0; nt < 4; nt++) {
            f32x4 a = {};
            a = __builtin_amdgcn_mfma_f32_16x16x32_bf16(kc0, qf[nt][0], a, 0, 0, 0);
            a = __builtin_amdgcn_mfma_f32_16x16x32_bf16(kc1, qf[nt][1], a, 0, 0, 0);
            st[nt] = a;
        }

        // causal mask on the diagonal tile: key_local > q_local -> -inf
        if (kt == qi) {
#pragma unroll
            for (int nt = 0; nt < 4; nt++)
#pragma unroll
                for (int r = 0; r < 4; r++)
                    if (wave * 16 + lg * 4 + r > nt * 16 + lq) st[nt][r] = -1e30f;
        }

        // P^T = exp2(St) (scores pre-scaled by log2e), pack to bf16, track l
        short4_t pf[4];
#pragma unroll
        for (int nt = 0; nt < 4; nt++) {
            float p0 = __builtin_amdgcn_exp2f(st[nt][0]);
            float p1 = __builtin_amdgcn_exp2f(st[nt][1]);
            float p2 = __builtin_amdgcn_exp2f(st[nt][2]);
            float p3 = __builtin_amdgcn_exp2f(st[nt][3]);
            l_lane[nt] += (p0 + p1) + (p2 + p3);
            bf16x4 pv;
            pv[0] = (bf16)p0; pv[1] = (bf16)p1; pv[2] = (bf16)p2; pv[3] = (bf16)p3;
            pf[nt] = __builtin_bit_cast(short4_t, pv);
        }

        // O^T += Vt(d x key16) * P^T   via mfma_f32_16x16x16_bf16
        short4_t va0 = __builtin_bit_cast(short4_t, vc0);
        short4_t va1 = __builtin_bit_cast(short4_t, vc1);
        short4_t va2 = __builtin_bit_cast(short4_t, vc2);
        short4_t va3 = __builtin_bit_cast(short4_t, vc3);
#pragma unroll
        for (int nt = 0; nt < 4; nt++) {
            o_acc[0][nt] = __builtin_amdgcn_mfma_f32_16x16x16bf16_1k(va0, pf[nt], o_acc[0][nt], 0, 0, 0);
            o_acc[1][nt] = __builtin_amdgcn_mfma_f32_16x16x16bf16_1k(va1, pf[nt], o_acc[1][nt], 0, 0, 0);
            o_acc[2][nt] = __builtin_amdgcn_mfma_f32_16x16x16bf16_1k(va2, pf[nt], o_acc[2][nt], 0, 0, 0);
            o_acc[3][nt] = __builtin_amdgcn_mfma_f32_16x16x16bf16_1k(va3, pf[nt], o_acc[3][nt], 0, 0, 0);
        }

        kc0 = kn0; kc1 = kn1;
        vc0 = vn0; vc1 = vn1; vc2 = vn2; vc3 = vn3;
    }

    // ---------------- epilogue: cross-wave reduction ----------------
    // per-wave l: sum over lg groups (lanes with equal lq), then stash
#pragma unroll
    for (int nt = 0; nt < 4; nt++) {
        float v = l_lane[nt];
        v += __shfl_xor(v, 16);
        v += __shfl_xor(v, 32);
        if (lg == 0) sL[wave * 64 + nt * 16 + lq] = v;
    }

    // O^T reduction rounds. Round rd: wave w handles slice dt=(w+rd)&3
    // (disjoint across waves); dtc compile-time constant via if-chain.
#pragma unroll
    for (int rd = 0; rd < 4; rd++) {
#pragma unroll
        for (int dtc = 0; dtc < 4; dtc++) {
            if (((wave + rd) & 3) == dtc) {
                if (rd == 0) {
#pragma unroll
                    for (int nt = 0; nt < 4; nt++)
#pragma unroll
                        for (int r = 0; r < 4; r++)
                            sO[(dtc * 16 + lg * 4 + r) * 65 + nt * 16 + lq] = o_acc[dtc][nt][r];
                } else {
#pragma unroll
                    for (int nt = 0; nt < 4; nt++)
#pragma unroll
                        for (int r = 0; r < 4; r++)
                            sO[(dtc * 16 + lg * 4 + r) * 65 + nt * 16 + lq] += o_acc[dtc][nt][r];
                }
            }
        }
        __syncthreads();
    }

    // final: wave stores dt=wave slice of O = O^T / l  (sink adds 1 to l)
    const int dt = wave;
    float rec[4];
#pragma unroll
    for (int nt = 0; nt < 4; nt++) {
        float lt = 1.0f + sL[nt * 16 + lq] + sL[64 + nt * 16 + lq]
                 + sL[128 + nt * 16 + lq] + sL[192 + nt * 16 + lq];
        rec[nt] = 1.0f / lt;
    }
#pragma unroll
    for (int nt = 0; nt < 4; nt++) {
        bf16x4 ov;
#pragma unroll
        for (int r = 0; r < 4; r++)
            ov[r] = (bf16)(sO[(dt * 16 + lg * 4 + r) * 65 + nt * 16 + lq] * rec[nt]);
        *(bf16x4*)&O[((size_t)(qb + nt * 16 + lq) * BATCH + b) * DMODEL + h * DHEAD + dt * 16 + lg * 4] = ov;
    }
}

// ---------------------------------------------------------------------------
extern "C" void kernel_launch(void* const* d_in, const int* in_sizes, int n_in,
                              void* d_out, int out_size, void* d_ws, size_t ws_size,
                              hipStream_t stream) {
    const float* x    = (const float*)d_in[0];
    // d_in[1] = attn_mask (pure causal -1e9; implemented structurally)
    const float* beta = (const float*)d_in[2];
    const float* Wq   = (const float*)d_in[3];
    const float* bq   = (const float*)d_in[4];
    const float* Wk   = (const float*)d_in[5];
    const float* bk   = (const float*)d_in[6];
    const float* Wv   = (const float*)d_in[7];
    const float* bv   = (const float*)d_in[8];
    const float* Wo   = (const float*)d_in[9];
    const float* bo   = (const float*)d_in[10];
    float* out = (float*)d_out;

    char* ws = (char*)d_ws;
    size_t off = 0;
    auto alloc = [&](size_t bytes) -> void* {
        void* p = ws + off;
        off += (bytes + 255) & ~(size_t)255;
        return p;
    };
    const size_t xbytes = (size_t)MROWS * DMODEL * sizeof(bf16);   // 16 MB
    const size_t wbytes = (size_t)DMODEL * DMODEL * sizeof(bf16);  // 2 MB
    bf16* xb  = (bf16*)alloc(xbytes);
    bf16* wqb = (bf16*)alloc(wbytes);
    bf16* wkb = (bf16*)alloc(wbytes);
    bf16* wvb = (bf16*)alloc(wbytes);
    bf16* wob = (bf16*)alloc(wbytes);
    bf16* qws = (bf16*)alloc(xbytes);
    bf16* kpb = (bf16*)alloc(xbytes);   // packed K
    bf16* vpb = (bf16*)alloc(xbytes);   // packed V
    bf16* aob = (bf16*)alloc(xbytes);

    const int nx8 = MROWS * DMODEL / 8;
    const int nw8 = DMODEL * DMODEL / 8;
    cast_bf16<<<(nx8 + 255) / 256, 256, 0, stream>>>(x, xb, nx8);
    cast_bf16<<<(nw8 + 255) / 256, 256, 0, stream>>>(Wq, wqb, nw8);
    cast_bf16<<<(nw8 + 255) / 256, 256, 0, stream>>>(Wk, wkb, nw8);
    cast_bf16<<<(nw8 + 255) / 256, 256, 0, stream>>>(Wv, wvb, nw8);
    cast_bf16<<<(nw8 + 255) / 256, 256, 0, stream>>>(Wo, wob, nw8);

    dim3 ggrid(DMODEL / 128, MROWS / 128);   // (8, 64)
    gemm_bt<0><<<ggrid, 256, 0, stream>>>(xb, wqb, bq, beta, qws);
    gemm_bt<1><<<ggrid, 256, 0, stream>>>(xb, wkb, bk, nullptr, kpb);
    gemm_bt<2><<<ggrid, 256, 0, stream>>>(xb, wvb, bv, nullptr, vpb);

    dim3 agrid(S_LEN / 64, NHEAD, BATCH);    // (32, 16, 4)
    attn_kernel<<<agrid, 256, 0, stream>>>(qws, kpb, vpb, aob);

    gemm_bt<3><<<ggrid, 256, 0, stream>>>(aob, wob, bo, nullptr, out);
}

// Round 7
// 308.739 us; speedup vs baseline: 1.4490x; 1.0395x over previous
//
#include <hip/hip_runtime.h>
#include <hip/hip_bf16.h>
#include <math.h>

// Problem constants
#define S_LEN   2048
#define BATCH   4
#define DMODEL  1024
#define NHEAD   16
#define DHEAD   64
#define MROWS   (S_LEN * BATCH)   // 8192 rows in flattened (s,b) order

typedef __bf16 bf16;
typedef __bf16 bf16x8 __attribute__((ext_vector_type(8)));
typedef __bf16 bf16x4 __attribute__((ext_vector_type(4)));
typedef short  short4_t __attribute__((ext_vector_type(4)));
typedef float  f32x4  __attribute__((ext_vector_type(4)));

#define LOG2E 1.4426950408889634f

// address-space casts for global_load_lds (direct global->LDS DMA)
#define AS1C(p) (const __attribute__((address_space(1))) void*)(p)
#define AS3(p)  (__attribute__((address_space(3))) void*)(p)

// Packed-layout definitions (per (b,h) slab of 128 key-tiles x 1024 elems):
//  Kp: tile T (16 keys): elem[T*1024 + c*512 + (s%16 + 16*(u>>3))*8 + (u&7)]
//      = K[s][dh], c=dh>>5, u=dh&31.  Wave fragment kf_c = 16B at lane*16.
//  Vp: tile T, d-tile dt: elem[T*1024 + dt*256 + (dh%16 + 16*((s%16)>>2))*4
//      + (s%16)&3] = V[s][dh].  Wave fragment va[dt] = 8B at lane*8.

// ---------------------------------------------------------------------------
// fp32 -> bf16 cast, 8 elems/thread
// ---------------------------------------------------------------------------
__global__ __launch_bounds__(256) void cast_bf16(const float* __restrict__ in,
                                                 bf16* __restrict__ out, int n8) {
    int i = blockIdx.x * 256 + threadIdx.x;
    if (i >= n8) return;
    const float4* p = (const float4*)in;
    float4 a = p[i * 2], b = p[i * 2 + 1];
    bf16x8 o;
    o[0] = (bf16)a.x; o[1] = (bf16)a.y; o[2] = (bf16)a.z; o[3] = (bf16)a.w;
    o[4] = (bf16)b.x; o[5] = (bf16)b.y; o[6] = (bf16)b.z; o[7] = (bf16)b.w;
    *(bf16x8*)(out + (size_t)i * 8) = o;
}

// 3-source cast: stacks Wq/Wk/Wv (each D*D fp32) into one (3D)*D bf16 buffer.
__global__ __launch_bounds__(256) void cast3_bf16(const float* __restrict__ w0,
                                                  const float* __restrict__ w1,
                                                  const float* __restrict__ w2,
                                                  bf16* __restrict__ out) {
    const int seg = blockIdx.y;                        // wave-uniform
    const float* in = (seg == 0) ? w0 : (seg == 1) ? w1 : w2;
    int i = blockIdx.x * 256 + threadIdx.x;            // 8-elem groups
    const float4* p = (const float4*)in;
    float4 a = p[i * 2], b = p[i * 2 + 1];
    bf16x8 o;
    o[0] = (bf16)a.x; o[1] = (bf16)a.y; o[2] = (bf16)a.z; o[3] = (bf16)a.w;
    o[4] = (bf16)b.x; o[5] = (bf16)b.y; o[6] = (bf16)b.z; o[7] = (bf16)b.w;
    *(bf16x8*)(out + (size_t)seg * DMODEL * DMODEL + (size_t)i * 8) = o;
}

// ---------------------------------------------------------------------------
// Shared GEMM core macro-equivalent: 128x128 tile, BK=32, m97-style
// global_load_lds staging. Used by qkv_gemm and gemm_out.
// ---------------------------------------------------------------------------
#define GEMM_CORE(A_, W_, KDIM_)                                                        \
    constexpr int BK = 32;                                                              \
    __shared__ __align__(16) bf16 sA[128 * BK];                                         \
    __shared__ __align__(16) bf16 sB[128 * BK];                                         \
    const int t    = threadIdx.x;                                                       \
    const int lane = t & 63;                                                            \
    const int wave = t >> 6;                                                            \
    const int bm = blockIdx.y * 128;                                                    \
    const int wm = (wave & 1) * 64;                                                     \
    const int wn = (wave >> 1) * 64;                                                    \
    const int lq = lane & 15;                                                           \
    const int lg = lane >> 4;                                                           \
    const int grow = wave * 32 + (lane >> 2);                                           \
    const int gcol = (lane & 3) * 8;                                                    \
    const bf16* Ap = A_ + (size_t)(bm + grow) * KDIM_ + gcol;                           \
    const bf16* Wp = W_ + (size_t)(bn + grow) * KDIM_ + gcol;                           \
    bf16* la0 = &sA[(wave * 32) * BK];                                                  \
    bf16* lb0 = &sB[(wave * 32) * BK];                                                  \
    f32x4 acc[4][4] = {};                                                               \
    for (int k0 = 0; k0 < KDIM_; k0 += BK) {                                            \
        __syncthreads();                                                                \
        __builtin_amdgcn_global_load_lds(AS1C(Ap + k0),                      AS3(la0),           16, 0, 0); \
        __builtin_amdgcn_global_load_lds(AS1C(Ap + (size_t)16 * KDIM_ + k0), AS3(la0 + 16 * BK), 16, 0, 0); \
        __builtin_amdgcn_global_load_lds(AS1C(Wp + k0),                      AS3(lb0),           16, 0, 0); \
        __builtin_amdgcn_global_load_lds(AS1C(Wp + (size_t)16 * KDIM_ + k0), AS3(lb0 + 16 * BK), 16, 0, 0); \
        __syncthreads();                                                                \
        const int koff = lg * 8;                                                        \
        bf16x8 af[4], bfr[4];                                                           \
        _Pragma("unroll")                                                               \
        for (int mt = 0; mt < 4; mt++)                                                  \
            af[mt] = *(const bf16x8*)&sA[(wm + mt * 16 + lq) * BK + koff];              \
        _Pragma("unroll")                                                               \
        for (int nt = 0; nt < 4; nt++)                                                  \
            bfr[nt] = *(const bf16x8*)&sB[(wn + nt * 16 + lq) * BK + koff];             \
        _Pragma("unroll")                                                               \
        for (int mt = 0; mt < 4; mt++)                                                  \
            _Pragma("unroll")                                                           \
            for (int nt = 0; nt < 4; nt++)                                              \
                acc[mt][nt] = __builtin_amdgcn_mfma_f32_16x16x32_bf16(                  \
                    af[mt], bfr[nt], acc[mt][nt], 0, 0, 0);                             \
    }                                                                                   \
    const int cr = lg * 4;                                                              \
    const int cc = lq;

// ---------------------------------------------------------------------------
// Fused QKV projection: A[8192,1024] x Wqkv[3072,1024]^T.
// n-segment 0 (cols 0..1023):    Q, scaled by log2e/(e^beta*8), row-major bf16
// n-segment 1 (cols 1024..2047): K, packed-fragment layout (Kp)
// n-segment 2 (cols 2048..3071): V, packed-fragment layout (Vp)
// ---------------------------------------------------------------------------
__global__ __launch_bounds__(256) void qkv_gemm(const bf16* __restrict__ A,
                                                const bf16* __restrict__ W,
                                                const float* __restrict__ bq,
                                                const float* __restrict__ bk,
                                                const float* __restrict__ bv,
                                                const float* __restrict__ beta,
                                                bf16* __restrict__ Qo,
                                                bf16* __restrict__ Kp,
                                                bf16* __restrict__ Vp) {
    const int bn = blockIdx.x * 128;         // global col base in [0, 3072)
    GEMM_CORE(A, W, DMODEL)

    const int seg = blockIdx.x >> 3;         // 0=Q, 1=K, 2=V (wave-uniform)
    const int bnl = (blockIdx.x & 7) * 128;  // col base within segment
    const float* bias = (seg == 0) ? bq : (seg == 1) ? bk : bv;

    if (seg == 0) {
#pragma unroll
        for (int nt = 0; nt < 4; nt++) {
            const int col = bnl + wn + nt * 16 + cc;
            const float bvv = bias[col];
            const float sc = LOG2E / (__expf(beta[col >> 6]) * 8.0f);
#pragma unroll
            for (int mt = 0; mt < 4; mt++) {
                const int row = bm + wm + mt * 16 + cr;
#pragma unroll
                for (int r = 0; r < 4; r++) {
                    float v = (acc[mt][nt][r] + bvv) * sc;
                    Qo[(size_t)(row + r) * DMODEL + col] = (bf16)v;
                }
            }
        }
    } else {
        bf16* out = (seg == 1) ? Kp : Vp;
        const int h = (bnl + wn) >> 6;       // wave-uniform head
#pragma unroll
        for (int mt = 0; mt < 4; mt++) {
            const int S0  = (bm + wm + mt * 16) >> 2;  // s of (lg=0,r=*)
            const int t16 = S0 >> 4;                   // key-tile index s/16
            const int m4  = (S0 >> 2) & 3;             // (S0&15)>>2
#pragma unroll
            for (int nt = 0; nt < 4; nt++) {
                const int col = bnl + wn + nt * 16 + cc;
                const float bvv = bias[col];
#pragma unroll
                for (int r = 0; r < 4; r++) {   // r = batch b
                    float v = acc[mt][nt][r] + bvv;
                    size_t addr;
                    if (seg == 1) {   // Kp
                        addr = ((size_t)((r * 16 + h) * 128 + t16)) * 1024
                             + (nt >> 1) * 512
                             + ((S0 & 15) + lg + 16 * ((nt & 1) * 2 + (lq >> 3))) * 8
                             + (lq & 7);
                    } else {          // Vp
                        addr = ((size_t)((r * 16 + h) * 128 + t16)) * 1024
                             + nt * 256 + (lq + 16 * m4) * 4 + lg;
                    }
                    out[addr] = (bf16)v;
                }
            }
        }
    }
}

// ---------------------------------------------------------------------------
// Output projection: A[8192,1024] x Wo[1024,1024]^T + bo -> f32
// ---------------------------------------------------------------------------
__global__ __launch_bounds__(256) void gemm_out(const bf16* __restrict__ A,
                                                const bf16* __restrict__ W,
                                                const float* __restrict__ bias,
                                                float* __restrict__ C) {
    const int bn = blockIdx.x * 128;
    GEMM_CORE(A, W, DMODEL)
#pragma unroll
    for (int nt = 0; nt < 4; nt++) {
        const int col = bn + wn + nt * 16 + cc;
        const float bvv = bias[col];
#pragma unroll
        for (int mt = 0; mt < 4; mt++) {
            const int row = bm + wm + mt * 16 + cr;
#pragma unroll
            for (int r = 0; r < 4; r++)
                C[(size_t)(row + r) * DMODEL + col] = acc[mt][nt][r] + bvv;
        }
    }
}

// ---------------------------------------------------------------------------
// Flash attention, causal + zero-sink, keys-split waves — barrier-free K-loop
// with coalesced packed-fragment loads; 1-deep register prefetch; LDS only in
// the epilogue. Register-array indices all compile-time constant.
// ---------------------------------------------------------------------------
__global__ __launch_bounds__(256, 3) void attn_kernel(const bf16* __restrict__ Q,
                                                      const bf16* __restrict__ Kp,
                                                      const bf16* __restrict__ Vp,
                                                      bf16* __restrict__ O) {
    __shared__ __align__(16) float sO[64 * 65];   // 16640 B (epilogue only)
    __shared__ __align__(16) float sL[256];       // 1024 B

    const int t    = threadIdx.x;
    const int lane = t & 63;
    const int wave = t >> 6;
    const int lq = lane & 15;
    const int lg = lane >> 4;
    const int qi = (int)gridDim.x - 1 - (int)blockIdx.x;  // heavy tiles first
    const int h = blockIdx.y;
    const int b = blockIdx.z;
    const int qb = qi * 64;

    // Loop-invariant Q fragments (B-operand of the St MFMA): [n=q][k=dh]
    bf16x8 qf[4][2];
#pragma unroll
    for (int nt = 0; nt < 4; nt++)
#pragma unroll
        for (int kc = 0; kc < 2; kc++)
            qf[nt][kc] = *(const bf16x8*)
                &Q[((size_t)(qb + nt * 16 + lq) * BATCH + b) * DMODEL + h * DHEAD + kc * 32 + lg * 8];

    f32x4 o_acc[4][4] = {};      // o_acc[dt][nt][r]: O^T row d=dt*16+lg*4+r, col q=nt*16+lq
    float l_lane[4] = {0.f, 0.f, 0.f, 0.f};

    const bf16* Kb = Kp + (size_t)(b * NHEAD + h) * 131072;   // 128 tiles * 1024
    const bf16* Vb = Vp + (size_t)(b * NHEAD + h) * 131072;

    bf16x8 kc0 = *(const bf16x8*)(Kb + (size_t)wave * 1024 + lane * 8);
    bf16x8 kc1 = *(const bf16x8*)(Kb + (size_t)wave * 1024 + 512 + lane * 8);
    bf16x4 vc0 = *(const bf16x4*)(Vb + (size_t)wave * 1024 +   0 + lane * 4);
    bf16x4 vc1 = *(const bf16x4*)(Vb + (size_t)wave * 1024 + 256 + lane * 4);
    bf16x4 vc2 = *(const bf16x4*)(Vb + (size_t)wave * 1024 + 512 + lane * 4);
    bf16x4 vc3 = *(const bf16x4*)(Vb + (size_t)wave * 1024 + 768 + lane * 4);

    for (int kt = 0; kt <= qi; kt++) {
        // prefetch next tile (wraps to tile 0 on last iter, unused)
        const int tn = ((kt < qi) ? (kt + 1) : 0) * 4 + wave;
        const bf16* Kn = Kb + (size_t)tn * 1024;
        const bf16* Vn = Vb + (size_t)tn * 1024;
        bf16x8 kn0 = *(const bf16x8*)(Kn + lane * 8);
        bf16x8 kn1 = *(const bf16x8*)(Kn + 512 + lane * 8);
        bf16x4 vn0 = *(const bf16x4*)(Vn +   0 + lane * 4);
        bf16x4 vn1 = *(const bf16x4*)(Vn + 256 + lane * 4);
        bf16x4 vn2 = *(const bf16x4*)(Vn + 512 + lane * 4);
        bf16x4 vn3 = *(const bf16x4*)(Vn + 768 + lane * 4);

        // St[key][q]: this wave's 16 keys x 64 q  (A = K rows, B = Q rows)
        f32x4 st[4];
#pragma unroll
        for (int nt = 0; nt < 4; nt++) {
            f32x4 a = {};
            a = __builtin_amdgcn_mfma_f32_16x16x32_bf16(kc0, qf[nt][0], a, 0, 0, 0);
            a = __builtin_amdgcn_mfma_f32_16x16x32_bf16(kc1, qf[nt][1], a, 0, 0, 0);
            st[nt] = a;
        }

        // causal mask on the diagonal tile: key_local > q_local -> -inf
        if (kt == qi) {
#pragma unroll
            for (int nt = 0; nt < 4; nt++)
#pragma unroll
                for (int r = 0; r < 4; r++)
                    if (wave * 16 + lg * 4 + r > nt * 16 + lq) st[nt][r] = -1e30f;
        }

        // P^T = exp2(St) (scores pre-scaled by log2e), pack to bf16, track l
        short4_t pf[4];
#pragma unroll
        for (int nt = 0; nt < 4; nt++) {
            float p0 = __builtin_amdgcn_exp2f(st[nt][0]);
            float p1 = __builtin_amdgcn_exp2f(st[nt][1]);
            float p2 = __builtin_amdgcn_exp2f(st[nt][2]);
            float p3 = __builtin_amdgcn_exp2f(st[nt][3]);
            l_lane[nt] += (p0 + p1) + (p2 + p3);
            bf16x4 pv;
            pv[0] = (bf16)p0; pv[1] = (bf16)p1; pv[2] = (bf16)p2; pv[3] = (bf16)p3;
            pf[nt] = __builtin_bit_cast(short4_t, pv);
        }

        // O^T += Vt(d x key16) * P^T   via mfma_f32_16x16x16_bf16
        short4_t va0 = __builtin_bit_cast(short4_t, vc0);
        short4_t va1 = __builtin_bit_cast(short4_t, vc1);
        short4_t va2 = __builtin_bit_cast(short4_t, vc2);
        short4_t va3 = __builtin_bit_cast(short4_t, vc3);
#pragma unroll
        for (int nt = 0; nt < 4; nt++) {
            o_acc[0][nt] = __builtin_amdgcn_mfma_f32_16x16x16bf16_1k(va0, pf[nt], o_acc[0][nt], 0, 0, 0);
            o_acc[1][nt] = __builtin_amdgcn_mfma_f32_16x16x16bf16_1k(va1, pf[nt], o_acc[1][nt], 0, 0, 0);
            o_acc[2][nt] = __builtin_amdgcn_mfma_f32_16x16x16bf16_1k(va2, pf[nt], o_acc[2][nt], 0, 0, 0);
            o_acc[3][nt] = __builtin_amdgcn_mfma_f32_16x16x16bf16_1k(va3, pf[nt], o_acc[3][nt], 0, 0, 0);
        }

        kc0 = kn0; kc1 = kn1;
        vc0 = vn0; vc1 = vn1; vc2 = vn2; vc3 = vn3;
    }

    // ---------------- epilogue: cross-wave reduction ----------------
#pragma unroll
    for (int nt = 0; nt < 4; nt++) {
        float v = l_lane[nt];
        v += __shfl_xor(v, 16);
        v += __shfl_xor(v, 32);
        if (lg == 0) sL[wave * 64 + nt * 16 + lq] = v;
    }

    // O^T reduction rounds. Round rd: wave w handles slice dt=(w+rd)&3
#pragma unroll
    for (int rd = 0; rd < 4; rd++) {
#pragma unroll
        for (int dtc = 0; dtc < 4; dtc++) {
            if (((wave + rd) & 3) == dtc) {
                if (rd == 0) {
#pragma unroll
                    for (int nt = 0; nt < 4; nt++)
#pragma unroll
                        for (int r = 0; r < 4; r++)
                            sO[(dtc * 16 + lg * 4 + r) * 65 + nt * 16 + lq] = o_acc[dtc][nt][r];
                } else {
#pragma unroll
                    for (int nt = 0; nt < 4; nt++)
#pragma unroll
                        for (int r = 0; r < 4; r++)
                            sO[(dtc * 16 + lg * 4 + r) * 65 + nt * 16 + lq] += o_acc[dtc][nt][r];
                }
            }
        }
        __syncthreads();
    }

    // final: wave stores dt=wave slice of O = O^T / l  (sink adds 1 to l)
    const int dt = wave;
    float rec[4];
#pragma unroll
    for (int nt = 0; nt < 4; nt++) {
        float lt = 1.0f + sL[nt * 16 + lq] + sL[64 + nt * 16 + lq]
                 + sL[128 + nt * 16 + lq] + sL[192 + nt * 16 + lq];
        rec[nt] = 1.0f / lt;
    }
#pragma unroll
    for (int nt = 0; nt < 4; nt++) {
        bf16x4 ov;
#pragma unroll
        for (int r = 0; r < 4; r++)
            ov[r] = (bf16)(sO[(dt * 16 + lg * 4 + r) * 65 + nt * 16 + lq] * rec[nt]);
        *(bf16x4*)&O[((size_t)(qb + nt * 16 + lq) * BATCH + b) * DMODEL + h * DHEAD + dt * 16 + lg * 4] = ov;
    }
}

// ---------------------------------------------------------------------------
extern "C" void kernel_launch(void* const* d_in, const int* in_sizes, int n_in,
                              void* d_out, int out_size, void* d_ws, size_t ws_size,
                              hipStream_t stream) {
    const float* x    = (const float*)d_in[0];
    // d_in[1] = attn_mask (pure causal -1e9; implemented structurally)
    const float* beta = (const float*)d_in[2];
    const float* Wq   = (const float*)d_in[3];
    const float* bq   = (const float*)d_in[4];
    const float* Wk   = (const float*)d_in[5];
    const float* bk   = (const float*)d_in[6];
    const float* Wv   = (const float*)d_in[7];
    const float* bv   = (const float*)d_in[8];
    const float* Wo   = (const float*)d_in[9];
    const float* bo   = (const float*)d_in[10];
    float* out = (float*)d_out;

    char* ws = (char*)d_ws;
    size_t off = 0;
    auto alloc = [&](size_t bytes) -> void* {
        void* p = ws + off;
        off += (bytes + 255) & ~(size_t)255;
        return p;
    };
    const size_t xbytes = (size_t)MROWS * DMODEL * sizeof(bf16);   // 16 MB
    const size_t wbytes = (size_t)DMODEL * DMODEL * sizeof(bf16);  // 2 MB
    bf16* xb   = (bf16*)alloc(xbytes);
    bf16* wqkv = (bf16*)alloc(3 * wbytes);   // stacked Wq/Wk/Wv
    bf16* wob  = (bf16*)alloc(wbytes);
    bf16* qws  = (bf16*)alloc(xbytes);
    bf16* kpb  = (bf16*)alloc(xbytes);   // packed K
    bf16* vpb  = (bf16*)alloc(xbytes);   // packed V
    bf16* aob  = (bf16*)alloc(xbytes);

    const int nx8 = MROWS * DMODEL / 8;
    const int nw8 = DMODEL * DMODEL / 8;
    cast_bf16<<<(nx8 + 255) / 256, 256, 0, stream>>>(x, xb, nx8);
    cast_bf16<<<(nw8 + 255) / 256, 256, 0, stream>>>(Wo, wob, nw8);
    dim3 c3grid(nw8 / 256, 3);
    cast3_bf16<<<c3grid, 256, 0, stream>>>(Wq, Wk, Wv, wqkv);

    dim3 qgrid(3 * DMODEL / 128, MROWS / 128);   // (24, 64)
    qkv_gemm<<<qgrid, 256, 0, stream>>>(xb, wqkv, bq, bk, bv, beta, qws, kpb, vpb);

    dim3 agrid(S_LEN / 64, NHEAD, BATCH);        // (32, 16, 4)
    attn_kernel<<<agrid, 256, 0, stream>>>(qws, kpb, vpb, aob);

    dim3 ogrid(DMODEL / 128, MROWS / 128);       // (8, 64)
    gemm_out<<<ogrid, 256, 0, stream>>>(aob, wob, bo, out);
}